// Round 21
// baseline (618.541 us; speedup 1.0000x reference)
//
#include <hip/hip_runtime.h>
#include <stdint.h>

#define NS   2048
#define NQ   6144
#define NN   8192      // total nodes
#define IND  512
#define DM   256
#define KNB  10
#define NSPLIT 8
#define PCAP 1536      // prop edge-list capacity per node
#define CSTR 32        // csr row stride (fallback to bitset walk if deg > CSTR)

#define AS1 __attribute__((address_space(1)))
#define AS3 __attribute__((address_space(3)))

typedef short bf16x8 __attribute__((ext_vector_type(8)));
typedef float f32x4  __attribute__((ext_vector_type(4)));
typedef unsigned long long u64;

// exact RNE fp32 -> bf16 (bits); bf16 exp range == fp32, no denormal hazard
__device__ __forceinline__ unsigned short f2bf(float v)
{
    unsigned int u = __float_as_uint(v);
    unsigned int r = (u + 0x7fffu + ((u >> 16) & 1u)) >> 16;
    return (unsigned short)r;
}
__device__ __forceinline__ float bf2f(unsigned short h)
{
    return __uint_as_float(((unsigned int)h) << 16);
}

// branchless 10-deep bubble insert of a u64 key (d2bits<<32 | j) into sorted-asc list
__device__ __forceinline__ void key_insert(u64 key, u64 K[KNB])
{
    u64 cur = key;
#pragma unroll
    for (int s = 0; s < KNB; ++s) {
        u64 lo = (cur < K[s]) ? cur : K[s];
        u64 hi = (cur < K[s]) ? K[s] : cur;
        K[s] = lo; cur = hi;
    }
}

// ---------- 0) pack W into transposed bf16 hi/lo MFMA fragments ----------
__global__ __launch_bounds__(256) void wpack_kernel(const float* __restrict__ W,
                                                    bf16x8* __restrict__ Wthi,
                                                    bf16x8* __restrict__ Wtlo)
{
    int f = blockIdx.x * 256 + threadIdx.x;       // 0..16383
    int dim = f & 255, qp = (f >> 8) & 3, c = f >> 10;
    int k0 = 32 * c + 8 * qp;
    bf16x8 h8, l8;
#pragma unroll
    for (int j = 0; j < 8; ++j) {
        float v = W[(size_t)(k0 + j) * DM + dim];
        unsigned short hu = f2bf(v);
        float hf = bf2f(hu);
        unsigned short lu = f2bf(v - hf);
        h8[j] = (short)hu; l8[j] = (short)lu;
    }
    Wthi[f] = h8; Wtlo[f] = l8;
}

// ---------- 1) embed via bf16-split MFMA (r13, validated absmax 0) ----------
__global__ __launch_bounds__(256) void embed_kernel(
    const float* __restrict__ support, const float* __restrict__ query,
    const bf16x8* __restrict__ Wthi, const bf16x8* __restrict__ Wtlo,
    bf16x8* __restrict__ Ghi, bf16x8* __restrict__ Glo, float* __restrict__ sq)
{
    __shared__ __align__(16) char lds[36928];
    bf16x8* Ehf = reinterpret_cast<bf16x8*>(lds);            // [1024] node frags (hi)
    bf16x8* Elf = Ehf + 1024;                                // [1024] (lo)
    float*  et  = reinterpret_cast<float*>(lds);             // epilogue alias: [16][260]
    float*  sqred = reinterpret_cast<float*>(lds + 32768);   // [16][65]
    const int t = threadIdx.x;
    const int l = t & 63, w = t >> 6;
    const int lm = l & 15, q = l >> 4;
    const int i0 = blockIdx.x * 16;

    {
        const int node = t & 15;
        const int g = i0 + node;
        const float* src = (g < NS) ? (support + (size_t)g * IND)
                                    : (query + (size_t)(g - NS) * IND);
#pragma unroll
        for (int i = 0; i < 4; ++i) {
            int cq = (t >> 4) + 16 * i;
            const float* p = src + cq * 8;
            float4 v0 = *reinterpret_cast<const float4*>(p);
            float4 v1 = *reinterpret_cast<const float4*>(p + 4);
            float vv[8] = {v0.x, v0.y, v0.z, v0.w, v1.x, v1.y, v1.z, v1.w};
            bf16x8 h8, l8;
#pragma unroll
            for (int j = 0; j < 8; ++j) {
                unsigned short hu = f2bf(vv[j]);
                float hf = bf2f(hu);
                unsigned short lu = f2bf(vv[j] - hf);
                h8[j] = (short)hu; l8[j] = (short)lu;
            }
            Ehf[cq * 16 + node] = h8;
            Elf[cq * 16 + node] = l8;
        }
    }
    __syncthreads();

    f32x4 acc[4];
#pragma unroll
    for (int nt = 0; nt < 4; ++nt) acc[nt] = (f32x4){0.f, 0.f, 0.f, 0.f};
    const int dimb = 64 * w + lm;
    for (int c = 0; c < 16; ++c) {
        const bf16x8 Anh = Ehf[(c * 4 + q) * 16 + lm];
        const bf16x8 Anl = Elf[(c * 4 + q) * 16 + lm];
        const int fb = c * 1024 + q * 256 + dimb;
#pragma unroll
        for (int nt = 0; nt < 4; ++nt) {
            const bf16x8 Wh = Wthi[fb + 16 * nt];
            const bf16x8 Wl = Wtlo[fb + 16 * nt];
            f32x4 a = acc[nt];
            a = __builtin_amdgcn_mfma_f32_16x16x32_bf16(Anh, Wh, a, 0, 0, 0);
            a = __builtin_amdgcn_mfma_f32_16x16x32_bf16(Anh, Wl, a, 0, 0, 0);
            a = __builtin_amdgcn_mfma_f32_16x16x32_bf16(Anl, Wh, a, 0, 0, 0);
            a = __builtin_amdgcn_mfma_f32_16x16x32_bf16(Anl, Wl, a, 0, 0, 0);
            acc[nt] = a;
        }
    }
    __syncthreads();                             // Ehf/Elf dead -> reuse as E-tile

#pragma unroll
    for (int r = 0; r < 4; ++r) {
        float s = 0.f;
#pragma unroll
        for (int nt = 0; nt < 4; ++nt) {
            float v = acc[nt][r];
            et[(4 * q + r) * 260 + dimb + 16 * nt] = v;
            s += v * v;
        }
        sqred[(4 * q + r) * 65 + w * 16 + lm] = s;
    }
    __syncthreads();

#pragma unroll
    for (int i = 0; i < 2; ++i) {
        int f = t + 256 * i;                     // 0..511 = 8 cd x 4 qd x 16 nodes
        int node = f & 15, qd = (f >> 4) & 3, cd = f >> 6;
        const float* ep = &et[node * 260 + 32 * cd + 8 * qd];
        bf16x8 h8, l8;
#pragma unroll
        for (int j = 0; j < 8; ++j) {
            float v = ep[j];
            unsigned short hu = f2bf(v);
            float hf = bf2f(hu);
            unsigned short lu = f2bf(v - hf);
            h8[j] = (short)hu; l8[j] = (short)lu;
        }
        size_t gi = (size_t)(cd * 4 + qd) * NN + i0 + node;
        Ghi[gi] = h8;
        Glo[gi] = l8;
    }
    if (t < 16) {
        float s = 0.f;
#pragma unroll
        for (int x = 0; x < 64; ++x) s += sqred[t * 65 + x];
        sq[i0 + t] = s;
    }
}

// ---------- 3) fused distance MFMA-GEMM + streaming per-row top-10 (r19, plateau) ----------
__global__ __launch_bounds__(256, 2) void dist_topk_kernel(
    const bf16x8* __restrict__ Ghi, const bf16x8* __restrict__ Glo,
    const float* __restrict__ sq, u64* __restrict__ cand)
{
    __shared__ bf16x8 stage[2][1024];            // 2 x 16 KB: [0,512)=hi, [512,1024)=lo; q-major
    __shared__ u64 stk[4][256];                  // 8 KB, slot-major per-thread stacks
    const int t  = threadIdx.x;
    const int l  = t & 63, w = t >> 6;
    const int lm = l & 15, q = l >> 4;
    const int i0 = blockIdx.x * 64;
    const int row = i0 + 16 * w + lm;            // this lane's row
    const int split = blockIdx.y;

    const float  sqi    = sq[row];
    const size_t rowIdx = (size_t)q * NN + row;  // row-frag index within a c-chunk (q-major)

    u64 K[KNB];
#pragma unroll
    for (int s = 0; s < KNB; ++s) K[s] = ~0ull;
    u64 thr = ~0ull;                             // lane-level: K[9]
    u64 thr_row = ~0ull;                         // row-level prune bound
    int cnt = 0;

    auto drain = [&]() {
        u64 live = __ballot(cnt > 0);
        while (live) {
            if (cnt > 0) {
                --cnt;
                u64 key = stk[cnt][t];
                if (key < thr) {
                    key_insert(key, K);
                    thr = K[KNB - 1];
                }
            }
            live = __ballot(cnt > 0);
        }
    };

    auto stage_issue = [&](int it, int b) {
        const int jt = split * 8 + (it >> 3);
        const int c  = it & 7;
        const int j0 = jt * 128;
        const size_t cbase = (size_t)c * (NN * 4);
        const bool hi = (w < 2);
        const int  wf = (w & 1) * 256;           // frag offset within hi/lo half
        const bf16x8* gsel = hi ? Ghi : Glo;
#pragma unroll
        for (int u = 0; u < 4; ++u) {
            const int f  = wf + u * 64;
            const int qr = f >> 7, col0 = f & 127;
            const bf16x8* g = gsel + cbase + (size_t)qr * NN + j0 + col0 + l;
            __builtin_amdgcn_global_load_lds((const AS1 void*)g,
                                             (AS3 void*)&stage[b][(hi ? 0 : 512) + f],
                                             16, 0, 0);
        }
    };

    stage_issue(0, 0);
    __syncthreads();                             // drains vmcnt -> stage 0 resident

    f32x4 acc[8];
    for (int it = 0; it < 64; ++it) {
        const int c = it & 7;
        const int b = it & 1;
        if (it + 1 < 64) stage_issue(it + 1, (it + 1) & 1);
        if (c == 0) {
#pragma unroll
            for (int mt = 0; mt < 8; ++mt) acc[mt] = (f32x4){0.f, 0.f, 0.f, 0.f};
        }
        const size_t co = (size_t)c * (NN * 4);
        const bf16x8 Bh = Ghi[co + rowIdx];      // row frags: tiny working set, L1/L2-hit
        const bf16x8 Bl = Glo[co + rowIdx];
        const bf16x8* sh = &stage[b][0];
        const bf16x8* sl = &stage[b][512];
        const int fq = q * 128 + lm;             // q-major frag base for this lane
#pragma unroll
        for (int mt = 0; mt < 8; ++mt) {
            const int fi = fq + 16 * mt;
            const bf16x8 Ah = sh[fi];
            const bf16x8 Al = sl[fi];
            f32x4 a = acc[mt];
            a = __builtin_amdgcn_mfma_f32_16x16x32_bf16(Ah, Bh, a, 0, 0, 0);
            a = __builtin_amdgcn_mfma_f32_16x16x32_bf16(Ah, Bl, a, 0, 0, 0);
            a = __builtin_amdgcn_mfma_f32_16x16x32_bf16(Al, Bh, a, 0, 0, 0);
            acc[mt] = a;                         // lo*lo dropped (3-product split, r19)
        }
        if (c == 7) {
            const int j0 = split * 1024 + (it >> 3) * 128;
#pragma unroll
            for (int mt = 0; mt < 8; ++mt) {
                const int jb = j0 + 16 * mt + 4 * q;
                const f32x4 sqj = *reinterpret_cast<const f32x4*>(&sq[jb]);
#pragma unroll
                for (int r = 0; r < 4; ++r) {
                    float d2 = fmaxf(sqi + sqj[r] - 2.0f * acc[mt][r], 0.0f);
                    u64 key = ((u64)__float_as_uint(d2) << 32) | (unsigned)(jb + r);
                    if (key < thr_row) { stk[cnt][t] = key; ++cnt; }   // cnt <= 3 (depth 4)
                }
                drain();
            }
            // refresh row-level prune bound (butterfly min over the 4 q-lanes of this row)
            u64 tr = K[KNB - 1];
            u64 o  = __shfl_xor(tr, 16, 64); tr = (o < tr) ? o : tr;
            o      = __shfl_xor(tr, 32, 64); tr = (o < tr) ? o : tr;
            thr_row = tr;
        }
        __syncthreads();   // consumers done with buf b; stage of it+1 drained (vmcnt)
    }
    // cross-q merge: dump region aliases other waves' stacks -> barrier first (r9 bug)
    __syncthreads();
    u64* dump = reinterpret_cast<u64*>(&stage[0][0]);    // 256*10*8 B = 20480 <= 32768
#pragma unroll
    for (int s = 0; s < KNB; ++s) dump[t * KNB + s] = K[s];
    if (q == 0) {
#pragma unroll
        for (int qq = 1; qq < 4; ++qq)
#pragma unroll
            for (int s = 0; s < KNB; ++s) {
                u64 key = dump[(t + qq * 16) * KNB + s];
                if (key < thr) {
                    key_insert(key, K);
                    thr = K[KNB - 1];
                }
            }
        size_t base = (size_t)row * (NSPLIT * KNB) + split * KNB;
#pragma unroll
        for (int s = 0; s < KNB; ++s) cand[base + s] = K[s];
    }
}

// ---------- 4) merge u64 partial lists -> global top-10, build adjacency bitset ----------
__global__ __launch_bounds__(64) void merge_adj_kernel(
    const u64* __restrict__ cand, unsigned int* __restrict__ bits)
{
    int i = blockIdx.x * 64 + threadIdx.x;
    if (i >= NN) return;
    const u64* cp = cand + (size_t)i * (NSPLIT * KNB);
    u64 K[KNB];
#pragma unroll
    for (int s = 0; s < KNB; ++s) K[s] = cp[s];   // split 0 already sorted asc
    u64 thr = K[KNB - 1];
    for (int s = KNB; s < NSPLIT * KNB; s += KNB) {
        u64 kk[KNB];
#pragma unroll
        for (int e = 0; e < KNB; ++e) kk[e] = cp[s + e];
#pragma unroll
        for (int e = 0; e < KNB; ++e) {
            if (kk[e] < thr) { key_insert(kk[e], K); thr = K[KNB - 1]; }
        }
    }
#pragma unroll
    for (int s = 0; s < KNB; ++s) {
        int j = (int)(K[s] & 0xFFFFFFFFu);
        atomicOr(&bits[(size_t)i * 256 + (j >> 5)], 1u << (j & 31));
        atomicOr(&bits[(size_t)j * 256 + (i >> 5)], 1u << (i & 31));
    }
}

// shared edge-list build: ordered (ascending j) per-node LDS list via shuffle prefix scan
__device__ __forceinline__ int build_list(const unsigned int* __restrict__ row,
                                          int c, int* __restrict__ lst)
{
    unsigned int mw[4];
#pragma unroll
    for (int k = 0; k < 4; ++k) mw[k] = row[4 * c + k];
    int cnt = __popc(mw[0]) + __popc(mw[1]) + __popc(mw[2]) + __popc(mw[3]);
    int incl = cnt;
#pragma unroll
    for (int d = 1; d < 64; d <<= 1) {
        int nb = __shfl_up(incl, d, 64);
        if (c >= d) incl += nb;
    }
    const int off = incl - cnt;
    const int deg = __shfl(incl, 63, 64);
    if (deg <= PCAP) {
        int p = off;
#pragma unroll
        for (int k = 0; k < 4; ++k) {
            unsigned int m = mw[k];
            while (m) {
                int b = __ffs(m) - 1;
                m &= m - 1;
                lst[p++] = (4 * c + k) * 32 + b;
            }
        }
    }
    return deg;
}

// bitset-walk gather fallback (exact ascending-j order)
__device__ __forceinline__ float walk_gather(const unsigned int* __restrict__ row,
                                             int c, float tinv,
                                             const float* __restrict__ lin)
{
    float acc = 0.f;
    for (int w2 = 0; w2 < 256; ++w2) {
        unsigned int m = row[w2];
        while (m) {
            int b = __ffs(m) - 1; m &= m - 1;
            int j = w2 * 32 + b;
            acc += __fmul_rn(tinv, lin[(size_t)j * 64 + c]);
        }
    }
    return acc;
}

// list gather: 8-wide batched loads, ascending-j order (bitwise identical to serial)
__device__ __forceinline__ float list_gather(const int* __restrict__ lst, int deg,
                                             int c, float tinv,
                                             const float* __restrict__ lin)
{
    float acc = 0.f;
    int d = 0;
    for (; d + 8 <= deg; d += 8) {
        float x[8];
#pragma unroll
        for (int e = 0; e < 8; ++e) x[e] = lin[(size_t)lst[d + e] * 64 + c];
#pragma unroll
        for (int e = 0; e < 8; ++e) acc += __fmul_rn(tinv, x[e]);
    }
    if (d + 4 <= deg) {
        float x[4];
#pragma unroll
        for (int e = 0; e < 4; ++e) x[e] = lin[(size_t)lst[d + e] * 64 + c];
#pragma unroll
        for (int e = 0; e < 4; ++e) acc += __fmul_rn(tinv, x[e]);
        d += 4;
    }
    for (; d < deg; ++d)
        acc += __fmul_rn(tinv, lin[(size_t)lst[d] * 64 + c]);
    return acc;
}

// csr-row gather: broadcast loads of the fixed-stride row, same order as list_gather
__device__ __forceinline__ float csr_gather(const int* __restrict__ crow, int deg,
                                            int c, float tinv,
                                            const float* __restrict__ lin)
{
    float acc = 0.f;
    int d = 0;
    for (; d + 8 <= deg; d += 8) {
        int jj[8];
#pragma unroll
        for (int e = 0; e < 8; ++e) jj[e] = crow[d + e];
        float x[8];
#pragma unroll
        for (int e = 0; e < 8; ++e) x[e] = lin[(size_t)jj[e] * 64 + c];
#pragma unroll
        for (int e = 0; e < 8; ++e) acc += __fmul_rn(tinv, x[e]);
    }
    if (d + 4 <= deg) {
        int jj[4];
#pragma unroll
        for (int e = 0; e < 4; ++e) jj[e] = crow[d + e];
        float x[4];
#pragma unroll
        for (int e = 0; e < 4; ++e) x[e] = lin[(size_t)jj[e] * 64 + c];
#pragma unroll
        for (int e = 0; e < 4; ++e) acc += __fmul_rn(tinv, x[e]);
        d += 4;
    }
    for (; d < deg; ++d)
        acc += __fmul_rn(tinv, lin[(size_t)crow[d] * 64 + c]);
    return acc;
}

// ---------- 6a) prop step 1 (labels_init fused) + CSR CACHE WRITE ----------
// Builds the edge list (needed for its own gather anyway), writes the one-hot
// propagation, AND caches the list (ascending j) + degree to global for reuse by
// the two later prop kernels. deg > CSTR nodes get no csr row (consumers fall
// back to the bitset walk -> exact either way).
__global__ __launch_bounds__(256) void prop_init_kernel(
    const unsigned int* __restrict__ bits, const int* __restrict__ slab,
    float* __restrict__ lout, int* __restrict__ csr, int* __restrict__ degA)
{
    __shared__ int lists[4][PCAP];
    const int grp = threadIdx.x >> 6;
    const int c   = threadIdx.x & 63;
    const int i   = blockIdx.x * 4 + grp;
    const unsigned int* row = bits + (size_t)i * 256;
    const int deg = build_list(row, c, lists[grp]);
    const float tinv = 1.0f / (float)deg;
    float acc = 0.f;
    if (deg <= PCAP) {
        const int* lst = lists[grp];
        for (int d = 0; d < deg; ++d) {
            int j = lst[d];
            float v = (j < NS && slab[j] == c) ? 1.0f : 0.0f;
            acc += __fmul_rn(tinv, v);
        }
    } else {
        for (int w2 = 0; w2 < 256; ++w2) {
            unsigned int m = row[w2];
            while (m) {
                int b = __ffs(m) - 1; m &= m - 1;
                int j = w2 * 32 + b;
                float v = (j < NS && slab[j] == c) ? 1.0f : 0.0f;
                acc += __fmul_rn(tinv, v);
            }
        }
    }
    lout[(size_t)i * 64 + c] = acc;
    // cache list + degree (same-wave LDS read after same-wave writes: lgkmcnt orders)
    if (c == 0) degA[i] = deg;
    if (deg <= CSTR && c < CSTR)
        csr[(size_t)i * CSTR + c] = (c < deg) ? lists[grp][c] : 0;
}

// ---------- 6b) prop step 2: CSR-cached gather (bitset fallback for hubs) ----------
__global__ __launch_bounds__(256) void prop_kernel(
    const unsigned int* __restrict__ bits, const int* __restrict__ csr,
    const int* __restrict__ degA, const float* __restrict__ lin,
    float* __restrict__ lout)
{
    const int grp = threadIdx.x >> 6;
    const int c   = threadIdx.x & 63;
    const int i   = blockIdx.x * 4 + grp;
    const int deg = degA[i];
    const float tinv = 1.0f / (float)deg;
    float acc;
    if (deg <= CSTR) acc = csr_gather(csr + (size_t)i * CSTR, deg, c, tinv, lin);
    else             acc = walk_gather(bits + (size_t)i * 256, c, tinv, lin);
    lout[(size_t)i * 64 + c] = acc;
}

// ---------- 6c) prop step 3 + argmax fused: QUERY ROWS ONLY -> one-hot out ----------
__global__ __launch_bounds__(256) void prop_argmax_kernel(
    const unsigned int* __restrict__ bits, const int* __restrict__ csr,
    const int* __restrict__ degA, const float* __restrict__ lin,
    float* __restrict__ out)
{
    const int grp = threadIdx.x >> 6;
    const int c   = threadIdx.x & 63;
    const int qn  = blockIdx.x * 4 + grp;          // query index 0..NQ-1
    const int i   = NS + qn;
    const int deg = degA[i];
    const float tinv = 1.0f / (float)deg;
    float acc;
    if (deg <= CSTR) acc = csr_gather(csr + (size_t)i * CSTR, deg, c, tinv, lin);
    else             acc = walk_gather(bits + (size_t)i * 256, c, tinv, lin);
    float bv = acc; int bi = c;
#pragma unroll
    for (int off = 32; off >= 1; off >>= 1) {
        float ov = __shfl_xor(bv, off, 64);
        int   oi = __shfl_xor(bi, off, 64);
        if (ov > bv || (ov == bv && oi < bi)) { bv = ov; bi = oi; }
    }
    out[(size_t)qn * 64 + c] = (c == bi) ? 1.0f : 0.0f;
}

// ---------- launch ----------
extern "C" void kernel_launch(void* const* d_in, const int* in_sizes, int n_in,
                              void* d_out, int out_size, void* d_ws, size_t ws_size,
                              hipStream_t stream)
{
    const float* support = (const float*)d_in[0];
    const float* query   = (const float*)d_in[1];
    const int*   slab    = (const int*)d_in[2];
    const float* W       = (const float*)d_in[3];
    float* out = (float*)d_out;
    char*  ws  = (char*)d_ws;

    // workspace (phase-aliased), total 13,664,256 B:
    //   [0, 8M)          Ghi+Glo -> bits after dist (8 MB, live through prop)
    //   [8M, +32K)       sq (dead after dist) -> degA (prop phase)
    //   [CV_OFF, +5.24M) Wthi/Wtlo (wpack->embed) / cand (dist->merge) ->
    //                    la [CV_OFF,+2M) + lb [CV_OFF+2M,+2M) + csr [CV_OFF+4M,+1M)
    const size_t GHI_OFF = 0;
    const size_t GLO_OFF = 4194304;
    const size_t SQ_OFF  = 8388608;
    const size_t CV_OFF  = 8421376;

    bf16x8*       Ghi  = (bf16x8*)(ws + GHI_OFF);
    bf16x8*       Glo  = (bf16x8*)(ws + GLO_OFF);
    unsigned int* bits = (unsigned int*)(ws + GHI_OFF);   // aliases Ghi/Glo (dead after dist)
    float*        sq   = (float*)(ws + SQ_OFF);
    int*          degA = (int*)  (ws + SQ_OFF);           // aliases sq (dead after dist)
    bf16x8*       Wthi = (bf16x8*)(ws + CV_OFF);          // dead before dist writes cand
    bf16x8*       Wtlo = (bf16x8*)(ws + CV_OFF + 262144);
    u64*          cand = (u64*)  (ws + CV_OFF);           // 8192 x 80 u64 = 5,242,880 B
    float*        lb   = (float*)(ws + CV_OFF);           // aliases cand (dead after merge)
    float*        la   = (float*)(ws + CV_OFF + 2097152);
    int*          csr  = (int*)  (ws + CV_OFF + 4194304); // 8192 x 32 int = 1,048,576 B

    wpack_kernel<<<64, 256, 0, stream>>>(W, Wthi, Wtlo);
    embed_kernel<<<512, 256, 0, stream>>>(support, query, Wthi, Wtlo, Ghi, Glo, sq);
    dist_topk_kernel<<<dim3(128, NSPLIT), 256, 0, stream>>>(Ghi, Glo, sq, cand);
    hipMemsetAsync(bits, 0, (size_t)NN * 256 * sizeof(unsigned int), stream);   // Ghi/Glo dead
    merge_adj_kernel<<<NN / 64, 64, 0, stream>>>(cand, bits);
    prop_init_kernel<<<NN / 4, 256, 0, stream>>>(bits, slab, lb, csr, degA);    // cand dead
    prop_kernel<<<NN / 4, 256, 0, stream>>>(bits, csr, degA, lb, la);
    prop_argmax_kernel<<<NQ / 4, 256, 0, stream>>>(bits, csr, degA, la, out);
}

// Round 22
// 417.370 us; speedup vs baseline: 1.4820x; 1.4820x over previous
//
#include <hip/hip_runtime.h>
#include <stdint.h>

#define NS   2048
#define NQ   6144
#define NN   8192      // total nodes
#define IND  512
#define DM   256
#define KNB  10
#define NSPLIT 8
#define PCAP 1536      // prop edge-list capacity per node

#define AS1 __attribute__((address_space(1)))
#define AS3 __attribute__((address_space(3)))

typedef short bf16x8 __attribute__((ext_vector_type(8)));
typedef float f32x4  __attribute__((ext_vector_type(4)));
typedef unsigned long long u64;

// exact RNE fp32 -> bf16 (bits); bf16 exp range == fp32, no denormal hazard
__device__ __forceinline__ unsigned short f2bf(float v)
{
    unsigned int u = __float_as_uint(v);
    unsigned int r = (u + 0x7fffu + ((u >> 16) & 1u)) >> 16;
    return (unsigned short)r;
}
__device__ __forceinline__ float bf2f(unsigned short h)
{
    return __uint_as_float(((unsigned int)h) << 16);
}

// branchless 10-deep bubble insert of a u64 key (d2bits<<32 | j) into sorted-asc list
__device__ __forceinline__ void key_insert(u64 key, u64 K[KNB])
{
    u64 cur = key;
#pragma unroll
    for (int s = 0; s < KNB; ++s) {
        u64 lo = (cur < K[s]) ? cur : K[s];
        u64 hi = (cur < K[s]) ? K[s] : cur;
        K[s] = lo; cur = hi;
    }
}

// ---------- 0) pack W into transposed bf16 hi/lo MFMA fragments ----------
__global__ __launch_bounds__(256) void wpack_kernel(const float* __restrict__ W,
                                                    bf16x8* __restrict__ Wthi,
                                                    bf16x8* __restrict__ Wtlo)
{
    int f = blockIdx.x * 256 + threadIdx.x;       // 0..16383
    int dim = f & 255, qp = (f >> 8) & 3, c = f >> 10;
    int k0 = 32 * c + 8 * qp;
    bf16x8 h8, l8;
#pragma unroll
    for (int j = 0; j < 8; ++j) {
        float v = W[(size_t)(k0 + j) * DM + dim];
        unsigned short hu = f2bf(v);
        float hf = bf2f(hu);
        unsigned short lu = f2bf(v - hf);
        h8[j] = (short)hu; l8[j] = (short)lu;
    }
    Wthi[f] = h8; Wtlo[f] = l8;
}

// ---------- 1) embed via bf16-split MFMA (r13, validated absmax 0) ----------
__global__ __launch_bounds__(256) void embed_kernel(
    const float* __restrict__ support, const float* __restrict__ query,
    const bf16x8* __restrict__ Wthi, const bf16x8* __restrict__ Wtlo,
    bf16x8* __restrict__ Ghi, bf16x8* __restrict__ Glo, float* __restrict__ sq)
{
    __shared__ __align__(16) char lds[36928];
    bf16x8* Ehf = reinterpret_cast<bf16x8*>(lds);            // [1024] node frags (hi)
    bf16x8* Elf = Ehf + 1024;                                // [1024] (lo)
    float*  et  = reinterpret_cast<float*>(lds);             // epilogue alias: [16][260]
    float*  sqred = reinterpret_cast<float*>(lds + 32768);   // [16][65]
    const int t = threadIdx.x;
    const int l = t & 63, w = t >> 6;
    const int lm = l & 15, q = l >> 4;
    const int i0 = blockIdx.x * 16;

    {
        const int node = t & 15;
        const int g = i0 + node;
        const float* src = (g < NS) ? (support + (size_t)g * IND)
                                    : (query + (size_t)(g - NS) * IND);
#pragma unroll
        for (int i = 0; i < 4; ++i) {
            int cq = (t >> 4) + 16 * i;
            const float* p = src + cq * 8;
            float4 v0 = *reinterpret_cast<const float4*>(p);
            float4 v1 = *reinterpret_cast<const float4*>(p + 4);
            float vv[8] = {v0.x, v0.y, v0.z, v0.w, v1.x, v1.y, v1.z, v1.w};
            bf16x8 h8, l8;
#pragma unroll
            for (int j = 0; j < 8; ++j) {
                unsigned short hu = f2bf(vv[j]);
                float hf = bf2f(hu);
                unsigned short lu = f2bf(vv[j] - hf);
                h8[j] = (short)hu; l8[j] = (short)lu;
            }
            Ehf[cq * 16 + node] = h8;
            Elf[cq * 16 + node] = l8;
        }
    }
    __syncthreads();

    f32x4 acc[4];
#pragma unroll
    for (int nt = 0; nt < 4; ++nt) acc[nt] = (f32x4){0.f, 0.f, 0.f, 0.f};
    const int dimb = 64 * w + lm;
    for (int c = 0; c < 16; ++c) {
        const bf16x8 Anh = Ehf[(c * 4 + q) * 16 + lm];
        const bf16x8 Anl = Elf[(c * 4 + q) * 16 + lm];
        const int fb = c * 1024 + q * 256 + dimb;
#pragma unroll
        for (int nt = 0; nt < 4; ++nt) {
            const bf16x8 Wh = Wthi[fb + 16 * nt];
            const bf16x8 Wl = Wtlo[fb + 16 * nt];
            f32x4 a = acc[nt];
            a = __builtin_amdgcn_mfma_f32_16x16x32_bf16(Anh, Wh, a, 0, 0, 0);
            a = __builtin_amdgcn_mfma_f32_16x16x32_bf16(Anh, Wl, a, 0, 0, 0);
            a = __builtin_amdgcn_mfma_f32_16x16x32_bf16(Anl, Wh, a, 0, 0, 0);
            a = __builtin_amdgcn_mfma_f32_16x16x32_bf16(Anl, Wl, a, 0, 0, 0);
            acc[nt] = a;
        }
    }
    __syncthreads();                             // Ehf/Elf dead -> reuse as E-tile

#pragma unroll
    for (int r = 0; r < 4; ++r) {
        float s = 0.f;
#pragma unroll
        for (int nt = 0; nt < 4; ++nt) {
            float v = acc[nt][r];
            et[(4 * q + r) * 260 + dimb + 16 * nt] = v;
            s += v * v;
        }
        sqred[(4 * q + r) * 65 + w * 16 + lm] = s;
    }
    __syncthreads();

#pragma unroll
    for (int i = 0; i < 2; ++i) {
        int f = t + 256 * i;                     // 0..511 = 8 cd x 4 qd x 16 nodes
        int node = f & 15, qd = (f >> 4) & 3, cd = f >> 6;
        const float* ep = &et[node * 260 + 32 * cd + 8 * qd];
        bf16x8 h8, l8;
#pragma unroll
        for (int j = 0; j < 8; ++j) {
            float v = ep[j];
            unsigned short hu = f2bf(v);
            float hf = bf2f(hu);
            unsigned short lu = f2bf(v - hf);
            h8[j] = (short)hu; l8[j] = (short)lu;
        }
        size_t gi = (size_t)(cd * 4 + qd) * NN + i0 + node;
        Ghi[gi] = h8;
        Glo[gi] = l8;
    }
    if (t < 16) {
        float s = 0.f;
#pragma unroll
        for (int x = 0; x < 64; ++x) s += sqred[t * 65 + x];
        sq[i0 + t] = s;
    }
}

// ---------- 3) fused distance MFMA-GEMM + streaming per-row top-10 (r19, plateau) ----------
__global__ __launch_bounds__(256, 2) void dist_topk_kernel(
    const bf16x8* __restrict__ Ghi, const bf16x8* __restrict__ Glo,
    const float* __restrict__ sq, u64* __restrict__ cand)
{
    __shared__ bf16x8 stage[2][1024];            // 2 x 16 KB: [0,512)=hi, [512,1024)=lo; q-major
    __shared__ u64 stk[4][256];                  // 8 KB, slot-major per-thread stacks
    const int t  = threadIdx.x;
    const int l  = t & 63, w = t >> 6;
    const int lm = l & 15, q = l >> 4;
    const int i0 = blockIdx.x * 64;
    const int row = i0 + 16 * w + lm;            // this lane's row
    const int split = blockIdx.y;

    const float  sqi    = sq[row];
    const size_t rowIdx = (size_t)q * NN + row;  // row-frag index within a c-chunk (q-major)

    u64 K[KNB];
#pragma unroll
    for (int s = 0; s < KNB; ++s) K[s] = ~0ull;
    u64 thr = ~0ull;                             // lane-level: K[9]
    u64 thr_row = ~0ull;                         // row-level prune bound
    int cnt = 0;

    auto drain = [&]() {
        u64 live = __ballot(cnt > 0);
        while (live) {
            if (cnt > 0) {
                --cnt;
                u64 key = stk[cnt][t];
                if (key < thr) {
                    key_insert(key, K);
                    thr = K[KNB - 1];
                }
            }
            live = __ballot(cnt > 0);
        }
    };

    auto stage_issue = [&](int it, int b) {
        const int jt = split * 8 + (it >> 3);
        const int c  = it & 7;
        const int j0 = jt * 128;
        const size_t cbase = (size_t)c * (NN * 4);
        const bool hi = (w < 2);
        const int  wf = (w & 1) * 256;           // frag offset within hi/lo half
        const bf16x8* gsel = hi ? Ghi : Glo;
#pragma unroll
        for (int u = 0; u < 4; ++u) {
            const int f  = wf + u * 64;
            const int qr = f >> 7, col0 = f & 127;
            const bf16x8* g = gsel + cbase + (size_t)qr * NN + j0 + col0 + l;
            __builtin_amdgcn_global_load_lds((const AS1 void*)g,
                                             (AS3 void*)&stage[b][(hi ? 0 : 512) + f],
                                             16, 0, 0);
        }
    };

    stage_issue(0, 0);
    __syncthreads();                             // drains vmcnt -> stage 0 resident

    f32x4 acc[8];
    for (int it = 0; it < 64; ++it) {
        const int c = it & 7;
        const int b = it & 1;
        if (it + 1 < 64) stage_issue(it + 1, (it + 1) & 1);
        if (c == 0) {
#pragma unroll
            for (int mt = 0; mt < 8; ++mt) acc[mt] = (f32x4){0.f, 0.f, 0.f, 0.f};
        }
        const size_t co = (size_t)c * (NN * 4);
        const bf16x8 Bh = Ghi[co + rowIdx];      // row frags: tiny working set, L1/L2-hit
        const bf16x8 Bl = Glo[co + rowIdx];
        const bf16x8* sh = &stage[b][0];
        const bf16x8* sl = &stage[b][512];
        const int fq = q * 128 + lm;             // q-major frag base for this lane
#pragma unroll
        for (int mt = 0; mt < 8; ++mt) {
            const int fi = fq + 16 * mt;
            const bf16x8 Ah = sh[fi];
            const bf16x8 Al = sl[fi];
            f32x4 a = acc[mt];
            a = __builtin_amdgcn_mfma_f32_16x16x32_bf16(Ah, Bh, a, 0, 0, 0);
            a = __builtin_amdgcn_mfma_f32_16x16x32_bf16(Ah, Bl, a, 0, 0, 0);
            a = __builtin_amdgcn_mfma_f32_16x16x32_bf16(Al, Bh, a, 0, 0, 0);
            acc[mt] = a;                         // lo*lo dropped (3-product split, r19)
        }
        if (c == 7) {
            const int j0 = split * 1024 + (it >> 3) * 128;
#pragma unroll
            for (int mt = 0; mt < 8; ++mt) {
                const int jb = j0 + 16 * mt + 4 * q;
                const f32x4 sqj = *reinterpret_cast<const f32x4*>(&sq[jb]);
#pragma unroll
                for (int r = 0; r < 4; ++r) {
                    float d2 = fmaxf(sqi + sqj[r] - 2.0f * acc[mt][r], 0.0f);
                    u64 key = ((u64)__float_as_uint(d2) << 32) | (unsigned)(jb + r);
                    if (key < thr_row) { stk[cnt][t] = key; ++cnt; }   // cnt <= 3 (depth 4)
                }
                drain();
            }
            // refresh row-level prune bound (butterfly min over the 4 q-lanes of this row)
            u64 tr = K[KNB - 1];
            u64 o  = __shfl_xor(tr, 16, 64); tr = (o < tr) ? o : tr;
            o      = __shfl_xor(tr, 32, 64); tr = (o < tr) ? o : tr;
            thr_row = tr;
        }
        __syncthreads();   // consumers done with buf b; stage of it+1 drained (vmcnt)
    }
    // cross-q merge: dump region aliases other waves' stacks -> barrier first (r9 bug)
    __syncthreads();
    u64* dump = reinterpret_cast<u64*>(&stage[0][0]);    // 256*10*8 B = 20480 <= 32768
#pragma unroll
    for (int s = 0; s < KNB; ++s) dump[t * KNB + s] = K[s];
    if (q == 0) {
#pragma unroll
        for (int qq = 1; qq < 4; ++qq)
#pragma unroll
            for (int s = 0; s < KNB; ++s) {
                u64 key = dump[(t + qq * 16) * KNB + s];
                if (key < thr) {
                    key_insert(key, K);
                    thr = K[KNB - 1];
                }
            }
        size_t base = (size_t)row * (NSPLIT * KNB) + split * KNB;
#pragma unroll
        for (int s = 0; s < KNB; ++s) cand[base + s] = K[s];
    }
}

// ---------- 4) merge u64 partial lists -> global top-10, build adjacency bitset ----------
__global__ __launch_bounds__(64) void merge_adj_kernel(
    const u64* __restrict__ cand, unsigned int* __restrict__ bits)
{
    int i = blockIdx.x * 64 + threadIdx.x;
    if (i >= NN) return;
    const u64* cp = cand + (size_t)i * (NSPLIT * KNB);
    u64 K[KNB];
#pragma unroll
    for (int s = 0; s < KNB; ++s) K[s] = cp[s];   // split 0 already sorted asc
    u64 thr = K[KNB - 1];
    for (int s = KNB; s < NSPLIT * KNB; s += KNB) {
        u64 kk[KNB];
#pragma unroll
        for (int e = 0; e < KNB; ++e) kk[e] = cp[s + e];
#pragma unroll
        for (int e = 0; e < KNB; ++e) {
            if (kk[e] < thr) { key_insert(kk[e], K); thr = K[KNB - 1]; }
        }
    }
#pragma unroll
    for (int s = 0; s < KNB; ++s) {
        int j = (int)(K[s] & 0xFFFFFFFFu);
        atomicOr(&bits[(size_t)i * 256 + (j >> 5)], 1u << (j & 31));
        atomicOr(&bits[(size_t)j * 256 + (i >> 5)], 1u << (i & 31));
    }
}

// shared edge-list build: ordered (ascending j) per-node LDS list via shuffle prefix scan
__device__ __forceinline__ int build_list(const unsigned int* __restrict__ row,
                                          int c, int* __restrict__ lst)
{
    unsigned int mw[4];
#pragma unroll
    for (int k = 0; k < 4; ++k) mw[k] = row[4 * c + k];
    int cnt = __popc(mw[0]) + __popc(mw[1]) + __popc(mw[2]) + __popc(mw[3]);
    int incl = cnt;
#pragma unroll
    for (int d = 1; d < 64; d <<= 1) {
        int nb = __shfl_up(incl, d, 64);
        if (c >= d) incl += nb;
    }
    const int off = incl - cnt;
    const int deg = __shfl(incl, 63, 64);
    if (deg <= PCAP) {
        int p = off;
#pragma unroll
        for (int k = 0; k < 4; ++k) {
            unsigned int m = mw[k];
            while (m) {
                int b = __ffs(m) - 1;
                m &= m - 1;
                lst[p++] = (4 * c + k) * 32 + b;
            }
        }
    }
    return deg;
}

// dense gather body shared by prop phases. 8-wide batched loads; accumulation
// ascending-j within and across batches -> bitwise identical to serial.
__device__ __forceinline__ float prop_gather(const unsigned int* __restrict__ row,
                                             int c, int* __restrict__ lst,
                                             const float* __restrict__ lin)
{
    const int deg = build_list(row, c, lst);
    const float tinv = 1.0f / (float)deg;
    float acc = 0.f;
    if (deg <= PCAP) {
        int d = 0;
        for (; d + 8 <= deg; d += 8) {
            float x[8];
#pragma unroll
            for (int e = 0; e < 8; ++e) x[e] = lin[(size_t)lst[d + e] * 64 + c];
#pragma unroll
            for (int e = 0; e < 8; ++e) acc += __fmul_rn(tinv, x[e]);
        }
        if (d + 4 <= deg) {
            float x[4];
#pragma unroll
            for (int e = 0; e < 4; ++e) x[e] = lin[(size_t)lst[d + e] * 64 + c];
#pragma unroll
            for (int e = 0; e < 4; ++e) acc += __fmul_rn(tinv, x[e]);
            d += 4;
        }
        for (; d < deg; ++d) {
            int j = lst[d];
            acc += __fmul_rn(tinv, lin[(size_t)j * 64 + c]);
        }
    } else {
        for (int w2 = 0; w2 < 256; ++w2) {
            unsigned int m = row[w2];
            while (m) {
                int b = __ffs(m) - 1; m &= m - 1;
                int j = w2 * 32 + b;
                acc += __fmul_rn(tinv, lin[(size_t)j * 64 + c]);
            }
        }
    }
    return acc;
}

__device__ __forceinline__ float prop_init_body(const unsigned int* __restrict__ row,
                                                int c, int* __restrict__ lst,
                                                const int* __restrict__ slab)
{
    const int deg = build_list(row, c, lst);
    const float tinv = 1.0f / (float)deg;
    float acc = 0.f;
    if (deg <= PCAP) {
        for (int d = 0; d < deg; ++d) {
            int j = lst[d];
            float v = (j < NS && slab[j] == c) ? 1.0f : 0.0f;
            acc += __fmul_rn(tinv, v);
        }
    } else {
        for (int w2 = 0; w2 < 256; ++w2) {
            unsigned int m = row[w2];
            while (m) {
                int b = __ffs(m) - 1; m &= m - 1;
                int j = w2 * 32 + b;
                float v = (j < NS && slab[j] == c) ? 1.0f : 0.0f;
                acc += __fmul_rn(tinv, v);
            }
        }
    }
    return acc;
}

// ---------- 6a) prop step 1 (labels_init fused) ----------
__global__ __launch_bounds__(256) void prop_init_kernel(
    const unsigned int* __restrict__ bits, const int* __restrict__ slab,
    float* __restrict__ lout)
{
    __shared__ int lists[4][PCAP];
    const int grp = threadIdx.x >> 6;
    const int c   = threadIdx.x & 63;
    const int i   = blockIdx.x * 4 + grp;
    const unsigned int* row = bits + (size_t)i * 256;
    lout[(size_t)i * 64 + c] = prop_init_body(row, c, lists[grp], slab);
}

// ---------- 6b) prop step 2 (dense gather) ----------
__global__ __launch_bounds__(256) void prop_kernel(
    const unsigned int* __restrict__ bits, const float* __restrict__ lin,
    float* __restrict__ lout)
{
    __shared__ int lists[4][PCAP];
    const int grp = threadIdx.x >> 6;
    const int c   = threadIdx.x & 63;
    const int i   = blockIdx.x * 4 + grp;
    const unsigned int* row = bits + (size_t)i * 256;
    lout[(size_t)i * 64 + c] = prop_gather(row, c, lists[grp], lin);
}

// ---------- 6c) prop step 3 + argmax fused: QUERY ROWS ONLY -> one-hot out ----------
__global__ __launch_bounds__(256) void prop_argmax_kernel(
    const unsigned int* __restrict__ bits, const float* __restrict__ lin,
    float* __restrict__ out)
{
    __shared__ int lists[4][PCAP];
    const int grp = threadIdx.x >> 6;
    const int c   = threadIdx.x & 63;
    const int qn  = blockIdx.x * 4 + grp;          // query index 0..NQ-1
    const int i   = NS + qn;
    const unsigned int* row = bits + (size_t)i * 256;
    float acc = prop_gather(row, c, lists[grp], lin);
    float bv = acc; int bi = c;
#pragma unroll
    for (int off = 32; off >= 1; off >>= 1) {
        float ov = __shfl_xor(bv, off, 64);
        int   oi = __shfl_xor(bi, off, 64);
        if (ov > bv || (ov == bv && oi < bi)) { bv = ov; bi = oi; }
    }
    out[(size_t)qn * 64 + c] = (c == bi) ? 1.0f : 0.0f;
}

// ---------- launch ----------
extern "C" void kernel_launch(void* const* d_in, const int* in_sizes, int n_in,
                              void* d_out, int out_size, void* d_ws, size_t ws_size,
                              hipStream_t stream)
{
    const float* support = (const float*)d_in[0];
    const float* query   = (const float*)d_in[1];
    const int*   slab    = (const int*)d_in[2];
    const float* W       = (const float*)d_in[3];
    float* out = (float*)d_out;
    char*  ws  = (char*)d_ws;

    const size_t GHI_OFF = 0;
    const size_t GLO_OFF = 4194304;
    const size_t SQ_OFF  = 8388608;
    const size_t CV_OFF  = 8421376;
    const size_t CI_OFF  = CV_OFF + (size_t)NN * NSPLIT * KNB * 4;   // +2,621,440

    bf16x8*       Ghi  = (bf16x8*)(ws + GHI_OFF);
    bf16x8*       Glo  = (bf16x8*)(ws + GLO_OFF);
    unsigned int* bits = (unsigned int*)(ws + GHI_OFF);   // aliases Ghi/Glo (dead after dist)
    float*        sq   = (float*)(ws + SQ_OFF);
    bf16x8*       Wthi = (bf16x8*)(ws + CV_OFF);          // dead before dist writes cand
    bf16x8*       Wtlo = (bf16x8*)(ws + CV_OFF + 262144);
    u64*          cand = (u64*)  (ws + CV_OFF);           // 8192 x 80 u64 = 5,242,880 B
    float*        la   = (float*)(ws + CV_OFF);           // aliases cand (dead after merge)
    float*        lb   = (float*)(ws + CI_OFF);

    wpack_kernel<<<64, 256, 0, stream>>>(W, Wthi, Wtlo);
    embed_kernel<<<512, 256, 0, stream>>>(support, query, Wthi, Wtlo, Ghi, Glo, sq);
    dist_topk_kernel<<<dim3(128, NSPLIT), 256, 0, stream>>>(Ghi, Glo, sq, cand);
    hipMemsetAsync(bits, 0, (size_t)NN * 256 * sizeof(unsigned int), stream);   // Ghi/Glo dead
    merge_adj_kernel<<<NN / 64, 64, 0, stream>>>(cand, bits);
    prop_init_kernel<<<NN / 4, 256, 0, stream>>>(bits, slab, lb);               // cand dead
    prop_kernel<<<NN / 4, 256, 0, stream>>>(bits, lb, la);
    prop_argmax_kernel<<<NQ / 4, 256, 0, stream>>>(bits, la, out);
}